// Round 3
// baseline (6944.502 us; speedup 1.0000x reference)
//
#include <hip/hip_runtime.h>
#include <math.h>

#define NN 1024
#define FF 128
#define DD 256
#define HH 8
#define CC 32
#define EE 32768
#define NEDGE (EE + NN)

__device__ __forceinline__ float sigf(float x) { return 1.0f / (1.0f + expf(-x)); }

// HW_REG_XCC_ID = 20, offset 0, size 32  (id | off<<6 | (size-1)<<11)
__device__ __forceinline__ int xcc_id() {
  return __builtin_amdgcn_s_getreg(20 | (31 << 11)) & 0xf;
}

// ---------------- CSR build (dst-indexed) ----------------
__global__ void k_count(const int* __restrict__ ei, int* __restrict__ count) {
  int k = blockIdx.x * blockDim.x + threadIdx.x;
  if (k >= NEDGE) return;
  int d = (k < EE) ? ei[EE + k] : (k - EE);
  atomicAdd(&count[d], 1);
}

__global__ void k_scan(const int* __restrict__ count, int* __restrict__ rowptr, int* __restrict__ cursor) {
  __shared__ int buf[NN];
  int t = threadIdx.x;
  int c = count[t];
  buf[t] = c;
  __syncthreads();
  for (int off = 1; off < NN; off <<= 1) {
    int add = (t >= off) ? buf[t - off] : 0;
    __syncthreads();
    buf[t] += add;
    __syncthreads();
  }
  int inc = buf[t];
  rowptr[t] = inc - c;
  cursor[t] = inc - c;
  if (t == NN - 1) rowptr[NN] = inc;
}

__global__ void k_scatter(const int* __restrict__ ei, int* __restrict__ cursor, int* __restrict__ csrc) {
  int k = blockIdx.x * blockDim.x + threadIdx.x;
  if (k >= NEDGE) return;
  int s, d;
  if (k < EE) { s = ei[k]; d = ei[EE + k]; }
  else        { s = k - EE; d = k - EE; }
  int pos = atomicAdd(&cursor[d], 1);
  csrc[pos] = s;
}

// ---------------- fp32 GEMM: C = A@B (or A@B^T) [+bias1+bias2] ----------------
template<bool BT, bool ADDB>
__global__ __launch_bounds__(256) void k_gemm(const float* __restrict__ A, const float* __restrict__ B,
    const float* __restrict__ bias1, const float* __restrict__ bias2, float* __restrict__ C,
    int M, int N, int K) {
  __shared__ float At[64][17];
  __shared__ float Bt[16][65];
  const int tid = threadIdx.x;
  const int m0 = blockIdx.x * 64, n0 = blockIdx.y * 64;
  const int tx = tid & 15, ty = tid >> 4;
  float acc[4][4] = {{0.f, 0.f, 0.f, 0.f}};
  for (int k0 = 0; k0 < K; k0 += 16) {
    {
      int rr = tid >> 2, kl = (tid & 3) * 4;
      float4 a = *(const float4*)(A + (m0 + rr) * K + k0 + kl);
      At[rr][kl] = a.x; At[rr][kl + 1] = a.y; At[rr][kl + 2] = a.z; At[rr][kl + 3] = a.w;
    }
    if (BT) {
      int nn = tid >> 2, kl = (tid & 3) * 4;
      float4 b = *(const float4*)(B + (n0 + nn) * K + k0 + kl);
      Bt[kl][nn] = b.x; Bt[kl + 1][nn] = b.y; Bt[kl + 2][nn] = b.z; Bt[kl + 3][nn] = b.w;
    } else {
      int kk = tid >> 4, nn = (tid & 15) * 4;
      float4 b = *(const float4*)(B + (k0 + kk) * N + n0 + nn);
      Bt[kk][nn] = b.x; Bt[kk][nn + 1] = b.y; Bt[kk][nn + 2] = b.z; Bt[kk][nn + 3] = b.w;
    }
    __syncthreads();
    #pragma unroll
    for (int kk = 0; kk < 16; ++kk) {
      float av[4], bv[4];
      #pragma unroll
      for (int i = 0; i < 4; ++i) av[i] = At[ty * 4 + i][kk];
      #pragma unroll
      for (int jj = 0; jj < 4; ++jj) bv[jj] = Bt[kk][tx * 4 + jj];
      #pragma unroll
      for (int i = 0; i < 4; ++i)
        #pragma unroll
        for (int jj = 0; jj < 4; ++jj)
          acc[i][jj] = fmaf(av[i], bv[jj], acc[i][jj]);
    }
    __syncthreads();
  }
  #pragma unroll
  for (int i = 0; i < 4; ++i) {
    #pragma unroll
    for (int jj = 0; jj < 4; ++jj) {
      int n = n0 + tx * 4 + jj;
      float v = acc[i][jj];
      if (ADDB) v += bias1[n] + bias2[n];
      C[(m0 + ty * 4 + i) * N + n] = v;
    }
  }
}

// ---------------- per-node attention scores es/ed ----------------
__global__ __launch_bounds__(256) void k_att(const float* __restrict__ h, const float* __restrict__ asrc,
    const float* __restrict__ adst, float* __restrict__ es, float* __restrict__ ed) {
  int n = blockIdx.x;
  int hd = threadIdx.x >> 5, c = threadIdx.x & 31;
  float hv = h[n * DD + hd * CC + c];
  float e1 = hv * asrc[hd * CC + c];
  float e2 = hv * adst[hd * CC + c];
  #pragma unroll
  for (int msk = 1; msk < 32; msk <<= 1) { e1 += __shfl_xor(e1, msk); e2 += __shfl_xor(e2, msk); }
  if (c == 0) { es[n * HH + hd] = e1; ed[n * HH + hd] = e2; }
}

// ---------------- per-(dst,head) softmax + aggregate (+bias, relu) ----------------
__global__ __launch_bounds__(256) void k_agg(const float* __restrict__ h, const float* __restrict__ es,
    const float* __restrict__ ed, const float* __restrict__ bias, const int* __restrict__ rowptr,
    const int* __restrict__ csrc, float* __restrict__ out) {
  int w = blockIdx.x * 4 + (threadIdx.x >> 6);
  int lane = threadIdx.x & 63;
  int n = w >> 3, hd = w & 7;
  int lo = rowptr[n], hi = rowptr[n + 1];
  float edn = ed[n * HH + hd];
  float m = -1e30f;
  for (int k = lo + lane; k < hi; k += 64) {
    int s = csrc[k];
    float e = es[s * HH + hd] + edn;
    e = (e > 0.f) ? e : 0.2f * e;
    m = fmaxf(m, e);
  }
  #pragma unroll
  for (int msk = 1; msk < 64; msk <<= 1) m = fmaxf(m, __shfl_xor(m, msk));
  float den = 0.f;
  for (int k = lo + lane; k < hi; k += 64) {
    int s = csrc[k];
    float e = es[s * HH + hd] + edn;
    e = (e > 0.f) ? e : 0.2f * e;
    den += expf(e - m);
  }
  #pragma unroll
  for (int msk = 1; msk < 64; msk <<= 1) den += __shfl_xor(den, msk);
  float inv = 1.0f / (den + 1e-16f);
  int c = lane & 31, halfsel = lane >> 5;
  float acc = 0.f;
  for (int k = lo + halfsel; k < hi; k += 2) {
    int s = csrc[k];
    float e = es[s * HH + hd] + edn;
    e = (e > 0.f) ? e : 0.2f * e;
    float al = expf(e - m) * inv;
    acc += al * h[s * DD + hd * CC + c];
  }
  acc += __shfl_down(acc, 32);
  if (lane < 32) {
    float v = acc + bias[hd * CC + c];
    out[n * DD + hd * CC + c] = fmaxf(v, 0.f);
  }
}

// ---------------- LSTM recurrence ----------------
// 8 elected blocks (same XCD preferred). Block role j owns columns [j*32, j*32+32)
// of all 4 gates. Handshake: tagged 8-byte (value|step) release-stores, parity
// double-buffered; readers poll the data word itself (single round trip).
__global__ __launch_bounds__(256, 1) void k_lstm(const float* __restrict__ xW,
    const float* __restrict__ Whh, unsigned long long* __restrict__ hpack,
    int* __restrict__ ctrl, float* __restrict__ hs) {
  const int t = threadIdx.x;
  __shared__ int s_role;
  if (t == 0) {
    int x = xcc_id();
    int ticket = atomicAdd(&ctrl[1 + x], 1);
    int role = -1;
    if (ticket < 8) {
      int prev = atomicCAS(&ctrl[0], 0, x + 1);
      if (prev == 0 || prev == x + 1) role = ticket;
    }
    s_role = role;
  }
  __syncthreads();
  const int j = s_role;
  if (j < 0) return;

  const int r = t >> 1, half = t & 1;
  const int g = r >> 5, kl = r & 31;
  const int grow = g * 256 + j * 32 + kl;
  __shared__ float hlds[DD];
  __shared__ float zlds[128];
  float4 w[32];
  {
    const float4* W4 = (const float4*)(Whh + grow * DD + half * 128);
    #pragma unroll
    for (int q = 0; q < 32; ++q) w[q] = W4[q];
  }
  if (t < DD) hlds[t] = 0.f;
  float creg = 0.f;
  __syncthreads();
  for (int s = 0; s < NN; ++s) {
    float xwv = xW[s * 1024 + grow];
    const float4* h4 = ((const float4*)hlds) + half * 32;
    float ac4[4] = {0.f, 0.f, 0.f, 0.f};
    #pragma unroll
    for (int q = 0; q < 32; ++q) {
      float4 hv = h4[q];
      ac4[q & 3] = fmaf(w[q].x, hv.x, ac4[q & 3]);
      ac4[q & 3] = fmaf(w[q].y, hv.y, ac4[q & 3]);
      ac4[q & 3] = fmaf(w[q].z, hv.z, ac4[q & 3]);
      ac4[q & 3] = fmaf(w[q].w, hv.w, ac4[q & 3]);
    }
    float acc = (ac4[0] + ac4[1]) + (ac4[2] + ac4[3]);
    acc += __shfl_xor(acc, 1);
    if (half == 0) zlds[r] = acc + xwv;
    __syncthreads();
    const int par = (s + 1) & 1;
    const unsigned int tag = (unsigned int)(s + 1);
    if (t < 32) {
      float iv = zlds[t], fv = zlds[32 + t], gv = zlds[64 + t], ov = zlds[96 + t];
      creg = sigf(fv) * creg + sigf(iv) * tanhf(gv);
      float hn = sigf(ov) * tanhf(creg);
      int col = j * 32 + t;
      hlds[col] = hn;
      hs[s * DD + col] = hn;
      unsigned long long pk = ((unsigned long long)__float_as_uint(hn) << 32) | tag;
      __hip_atomic_store(&hpack[par * DD + col], pk, __ATOMIC_RELEASE, __HIP_MEMORY_SCOPE_AGENT);
    }
    if (t < 224) {
      int po = t >> 5;
      int peer = j + 1 + po; if (peer >= 8) peer -= 8;
      int col = peer * 32 + (t & 31);
      unsigned long long v;
      while (((v = __hip_atomic_load(&hpack[par * DD + col], __ATOMIC_ACQUIRE,
                                     __HIP_MEMORY_SCOPE_AGENT)) & 0xffffffffULL) != tag) {
        __builtin_amdgcn_s_sleep(1);
      }
      hlds[col] = __uint_as_float((unsigned int)(v >> 32));
    }
    __syncthreads();
  }
}

// ---------------- final per-edge outputs ----------------
__global__ __launch_bounds__(256) void k_edges(const float* __restrict__ hs, const int* __restrict__ ei,
    const float* __restrict__ Wp, const float* __restrict__ bp,
    const float* __restrict__ Wc, const float* __restrict__ bc, float* __restrict__ out) {
  int widx = threadIdx.x >> 6, lane = threadIdx.x & 63;
  int k = blockIdx.x * 4 + widx;
  int sIdx = ei[k], dIdx = ei[EE + k];
  float4 u = ((const float4*)(hs + sIdx * DD))[lane];
  float4 v = ((const float4*)(hs + dIdx * DD))[lane];
  float4 wp = ((const float4*)Wp)[lane];
  float4 wc = ((const float4*)Wc)[lane];
  float x0 = u.x * v.x, x1 = u.y * v.y, x2 = u.z * v.z, x3 = u.w * v.w;
  float ap = x0 * wp.x + x1 * wp.y + x2 * wp.z + x3 * wp.w;
  float ac = x0 * wc.x + x1 * wc.y + x2 * wc.z + x3 * wc.w;
  #pragma unroll
  for (int msk = 1; msk < 64; msk <<= 1) { ap += __shfl_xor(ap, msk); ac += __shfl_xor(ac, msk); }
  if (lane == 0) { out[k] = ap + bp[0]; out[EE + k] = ac + bc[0]; }
}

extern "C" void kernel_launch(void* const* d_in, const int* in_sizes, int n_in,
                              void* d_out, int out_size, void* d_ws, size_t ws_size,
                              hipStream_t stream) {
  const float* x       = (const float*)d_in[0];
  const int* ei        = (const int*)d_in[1];
  const float* W1      = (const float*)d_in[3];
  const float* as1     = (const float*)d_in[4];
  const float* ad1     = (const float*)d_in[5];
  const float* b1      = (const float*)d_in[6];
  const float* W2      = (const float*)d_in[7];
  const float* as2     = (const float*)d_in[8];
  const float* ad2     = (const float*)d_in[9];
  const float* b2      = (const float*)d_in[10];
  const float* Wih     = (const float*)d_in[11];
  const float* Whh     = (const float*)d_in[12];
  const float* bih     = (const float*)d_in[13];
  const float* bhh     = (const float*)d_in[14];
  const float* Wp      = (const float*)d_in[15];
  const float* bp      = (const float*)d_in[16];
  const float* Wc      = (const float*)d_in[17];
  const float* bc      = (const float*)d_in[18];
  float* out = (float*)d_out;

  char* ws = (char*)d_ws;
  int* counts                   = (int*)(ws + 0);        // 4 KB   [memset]
  int* ctrl                     = (int*)(ws + 4096);     // 4 KB   [memset] chosen + perXcd tickets
  unsigned long long* hpack     = (unsigned long long*)(ws + 8192);  // 4 KB [memset]
  int* rowptr                   = (int*)(ws + 12288);    // 8 KB
  int* cursor                   = (int*)(ws + 20480);    // 4 KB
  int* csrc                     = (int*)(ws + 24576);    // 136 KB
  float* es                     = (float*)(ws + 163840); // 32 KB
  float* ed                     = (float*)(ws + 196608); // 32 KB
  float* buf0                   = (float*)(ws + 229376); // 1 MB
  float* buf1                   = (float*)(ws + 1277952);// 1 MB
  float* xW                     = (float*)(ws + 2326528);// 4 MB
  float* hsall                  = (float*)(ws + 6520832);// 1 MB

  // zero counts + election ctrl + handshake tags (in-graph => reset on every replay)
  hipMemsetAsync(ws, 0, 12288, stream);

  // CSR by dst (E edges + N self-loops)
  k_count  <<<(NEDGE + 255) / 256, 256, 0, stream>>>(ei, counts);
  k_scan   <<<1, 1024, 0, stream>>>(counts, rowptr, cursor);
  k_scatter<<<(NEDGE + 255) / 256, 256, 0, stream>>>(ei, cursor, csrc);

  // GAT layer 1 (graph (0,0) only)
  k_gemm<false, false><<<dim3(16, 4), 256, 0, stream>>>(x, W1, nullptr, nullptr, buf0, NN, DD, FF);
  k_att<<<NN, 256, 0, stream>>>(buf0, as1, ad1, es, ed);
  k_agg<<<NN * HH / 4, 256, 0, stream>>>(buf0, es, ed, b1, rowptr, csrc, buf1);

  // GAT layer 2
  k_gemm<false, false><<<dim3(16, 4), 256, 0, stream>>>(buf1, W2, nullptr, nullptr, buf0, NN, DD, DD);
  k_att<<<NN, 256, 0, stream>>>(buf0, as2, ad2, es, ed);
  k_agg<<<NN * HH / 4, 256, 0, stream>>>(buf0, es, ed, b2, rowptr, csrc, buf1);

  // LSTM input projection: xW[n, j] = h2[n,:]·Wih[j,:] + bih[j] + bhh[j]
  k_gemm<true, true><<<dim3(16, 16), 256, 0, stream>>>(buf1, Wih, bih, bhh, xW, NN, 1024, DD);

  // sequential recurrence; 512 candidates, 8 elected (same-XCD preferred)
  k_lstm<<<512, 256, 0, stream>>>(xW, Whh, hpack, ctrl, hsall);

  // final per-edge predictions
  k_edges<<<EE / 4, 256, 0, stream>>>(hsall, ei, Wp, bp, Wc, bc, out);
}

// Round 4
// 3443.714 us; speedup vs baseline: 2.0166x; 2.0166x over previous
//
#include <hip/hip_runtime.h>
#include <math.h>

#define NN 1024
#define FF 128
#define DD 256
#define HH 8
#define CC 32
#define EE 32768
#define NEDGE (EE + NN)

__device__ __forceinline__ float sigf(float x) { return 1.0f / (1.0f + expf(-x)); }

// HW_REG_XCC_ID = 20, offset 0, size 32
__device__ __forceinline__ int xcc_id() {
  return __builtin_amdgcn_s_getreg(20 | (31 << 11)) & 0xf;
}

// L2-coherent (XCD-local) 8-byte store/load: sc0 bypasses L1 only.
__device__ __forceinline__ void store_l2(unsigned long long* p, unsigned long long v) {
  asm volatile("global_store_dwordx2 %0, %1, off sc0" :: "v"(p), "v"(v) : "memory");
}
__device__ __forceinline__ unsigned long long load_l2(const unsigned long long* p) {
  unsigned long long r;
  asm volatile("global_load_dwordx2 %0, %1, off sc0\n\ts_waitcnt vmcnt(0)"
               : "=v"(r) : "v"(p) : "memory");
  return r;
}

// ---------------- CSR build (dst-indexed) ----------------
__global__ void k_count(const int* __restrict__ ei, int* __restrict__ count) {
  int k = blockIdx.x * blockDim.x + threadIdx.x;
  if (k >= NEDGE) return;
  int d = (k < EE) ? ei[EE + k] : (k - EE);
  atomicAdd(&count[d], 1);
}

__global__ void k_scan(const int* __restrict__ count, int* __restrict__ rowptr, int* __restrict__ cursor) {
  __shared__ int buf[NN];
  int t = threadIdx.x;
  int c = count[t];
  buf[t] = c;
  __syncthreads();
  for (int off = 1; off < NN; off <<= 1) {
    int add = (t >= off) ? buf[t - off] : 0;
    __syncthreads();
    buf[t] += add;
    __syncthreads();
  }
  int inc = buf[t];
  rowptr[t] = inc - c;
  cursor[t] = inc - c;
  if (t == NN - 1) rowptr[NN] = inc;
}

__global__ void k_scatter(const int* __restrict__ ei, int* __restrict__ cursor, int* __restrict__ csrc) {
  int k = blockIdx.x * blockDim.x + threadIdx.x;
  if (k >= NEDGE) return;
  int s, d;
  if (k < EE) { s = ei[k]; d = ei[EE + k]; }
  else        { s = k - EE; d = k - EE; }
  int pos = atomicAdd(&cursor[d], 1);
  csrc[pos] = s;
}

// ---------------- fp32 GEMM: C = A@B (or A@B^T) [+bias1+bias2] ----------------
template<bool BT, bool ADDB>
__global__ __launch_bounds__(256) void k_gemm(const float* __restrict__ A, const float* __restrict__ B,
    const float* __restrict__ bias1, const float* __restrict__ bias2, float* __restrict__ C,
    int M, int N, int K) {
  __shared__ float At[64][17];
  __shared__ float Bt[16][65];
  const int tid = threadIdx.x;
  const int m0 = blockIdx.x * 64, n0 = blockIdx.y * 64;
  const int tx = tid & 15, ty = tid >> 4;
  float acc[4][4] = {{0.f, 0.f, 0.f, 0.f}};
  for (int k0 = 0; k0 < K; k0 += 16) {
    {
      int rr = tid >> 2, kl = (tid & 3) * 4;
      float4 a = *(const float4*)(A + (m0 + rr) * K + k0 + kl);
      At[rr][kl] = a.x; At[rr][kl + 1] = a.y; At[rr][kl + 2] = a.z; At[rr][kl + 3] = a.w;
    }
    if (BT) {
      int nn = tid >> 2, kl = (tid & 3) * 4;
      float4 b = *(const float4*)(B + (n0 + nn) * K + k0 + kl);
      Bt[kl][nn] = b.x; Bt[kl + 1][nn] = b.y; Bt[kl + 2][nn] = b.z; Bt[kl + 3][nn] = b.w;
    } else {
      int kk = tid >> 4, nn = (tid & 15) * 4;
      float4 b = *(const float4*)(B + (k0 + kk) * N + n0 + nn);
      Bt[kk][nn] = b.x; Bt[kk][nn + 1] = b.y; Bt[kk][nn + 2] = b.z; Bt[kk][nn + 3] = b.w;
    }
    __syncthreads();
    #pragma unroll
    for (int kk = 0; kk < 16; ++kk) {
      float av[4], bv[4];
      #pragma unroll
      for (int i = 0; i < 4; ++i) av[i] = At[ty * 4 + i][kk];
      #pragma unroll
      for (int jj = 0; jj < 4; ++jj) bv[jj] = Bt[kk][tx * 4 + jj];
      #pragma unroll
      for (int i = 0; i < 4; ++i)
        #pragma unroll
        for (int jj = 0; jj < 4; ++jj)
          acc[i][jj] = fmaf(av[i], bv[jj], acc[i][jj]);
    }
    __syncthreads();
  }
  #pragma unroll
  for (int i = 0; i < 4; ++i) {
    #pragma unroll
    for (int jj = 0; jj < 4; ++jj) {
      int n = n0 + tx * 4 + jj;
      float v = acc[i][jj];
      if (ADDB) v += bias1[n] + bias2[n];
      C[(m0 + ty * 4 + i) * N + n] = v;
    }
  }
}

// ---------------- per-node attention scores es/ed ----------------
__global__ __launch_bounds__(256) void k_att(const float* __restrict__ h, const float* __restrict__ asrc,
    const float* __restrict__ adst, float* __restrict__ es, float* __restrict__ ed) {
  int n = blockIdx.x;
  int hd = threadIdx.x >> 5, c = threadIdx.x & 31;
  float hv = h[n * DD + hd * CC + c];
  float e1 = hv * asrc[hd * CC + c];
  float e2 = hv * adst[hd * CC + c];
  #pragma unroll
  for (int msk = 1; msk < 32; msk <<= 1) { e1 += __shfl_xor(e1, msk); e2 += __shfl_xor(e2, msk); }
  if (c == 0) { es[n * HH + hd] = e1; ed[n * HH + hd] = e2; }
}

// ---------------- per-(dst,head) softmax + aggregate (+bias, relu) ----------------
__global__ __launch_bounds__(256) void k_agg(const float* __restrict__ h, const float* __restrict__ es,
    const float* __restrict__ ed, const float* __restrict__ bias, const int* __restrict__ rowptr,
    const int* __restrict__ csrc, float* __restrict__ out) {
  int w = blockIdx.x * 4 + (threadIdx.x >> 6);
  int lane = threadIdx.x & 63;
  int n = w >> 3, hd = w & 7;
  int lo = rowptr[n], hi = rowptr[n + 1];
  float edn = ed[n * HH + hd];
  float m = -1e30f;
  for (int k = lo + lane; k < hi; k += 64) {
    int s = csrc[k];
    float e = es[s * HH + hd] + edn;
    e = (e > 0.f) ? e : 0.2f * e;
    m = fmaxf(m, e);
  }
  #pragma unroll
  for (int msk = 1; msk < 64; msk <<= 1) m = fmaxf(m, __shfl_xor(m, msk));
  float den = 0.f;
  for (int k = lo + lane; k < hi; k += 64) {
    int s = csrc[k];
    float e = es[s * HH + hd] + edn;
    e = (e > 0.f) ? e : 0.2f * e;
    den += expf(e - m);
  }
  #pragma unroll
  for (int msk = 1; msk < 64; msk <<= 1) den += __shfl_xor(den, msk);
  float inv = 1.0f / (den + 1e-16f);
  int c = lane & 31, halfsel = lane >> 5;
  float acc = 0.f;
  for (int k = lo + halfsel; k < hi; k += 2) {
    int s = csrc[k];
    float e = es[s * HH + hd] + edn;
    e = (e > 0.f) ? e : 0.2f * e;
    float al = expf(e - m) * inv;
    acc += al * h[s * DD + hd * CC + c];
  }
  acc += __shfl_down(acc, 32);
  if (lane < 32) {
    float v = acc + bias[hd * CC + c];
    out[n * DD + hd * CC + c] = fmaxf(v, 0.f);
  }
}

// ---------------- LSTM recurrence ----------------
// 8 blocks elected onto ONE XCD. Handshake = self-tagged u64 (h-bits<<32 | step)
// stored with sc0 (XCD-L2 coherent, L1 bypass). No fences needed: tag+payload are
// one atom. Dual-published to an agent-scope (LLC) mirror; consumers fall back to
// it after a bounded fast-poll timeout => never hangs, worst case = LLC latency.
__global__ __launch_bounds__(256, 1) void k_lstm(const float* __restrict__ xW,
    const float* __restrict__ Whh, unsigned long long* __restrict__ fastw,
    unsigned long long* __restrict__ sloww, int* __restrict__ ctrl,
    float* __restrict__ hs) {
  const int t = threadIdx.x;
  __shared__ int s_role;
  if (t == 0) {
    int x = xcc_id();
    int ticket = atomicAdd(&ctrl[1 + x], 1);
    int role = -1;
    if (ticket < 8) {
      int prev = atomicCAS(&ctrl[0], 0, x + 1);
      if (prev == 0 || prev == x + 1) role = ticket;
    }
    s_role = role;
  }
  __syncthreads();
  const int j = s_role;
  if (j < 0) return;

  // one-time init: role 0 zeroes the fast region THROUGH THE WINNER L2 (kills
  // arbitrary initial ws content), then raises an agent-scope ready flag.
  if (j == 0) {
    store_l2(&fastw[t], 0ULL);
    store_l2(&fastw[256 + t], 0ULL);
    asm volatile("s_waitcnt vmcnt(0)" ::: "memory");
    __syncthreads();
    if (t == 0) __hip_atomic_store(&ctrl[32], 1, __ATOMIC_RELEASE, __HIP_MEMORY_SCOPE_AGENT);
  } else {
    if (t == 0) {
      while (__hip_atomic_load(&ctrl[32], __ATOMIC_ACQUIRE, __HIP_MEMORY_SCOPE_AGENT) == 0)
        __builtin_amdgcn_s_sleep(2);
    }
    __syncthreads();
  }

  const int r = t >> 1, half = t & 1;
  const int g = r >> 5, kl = r & 31;
  const int grow = g * 256 + j * 32 + kl;
  __shared__ float hlds[DD];
  __shared__ float zlds[128];
  float4 w[32];
  {
    const float4* W4 = (const float4*)(Whh + grow * DD + half * 128);
    #pragma unroll
    for (int q = 0; q < 32; ++q) w[q] = W4[q];
  }
  if (t < DD) hlds[t] = 0.f;
  float creg = 0.f;
  float xwv = xW[grow];
  __syncthreads();
  for (int s = 0; s < NN; ++s) {
    const float4* h4 = ((const float4*)hlds) + half * 32;
    float ac4[4] = {0.f, 0.f, 0.f, 0.f};
    #pragma unroll
    for (int q = 0; q < 32; ++q) {
      float4 hv = h4[q];
      ac4[q & 3] = fmaf(w[q].x, hv.x, ac4[q & 3]);
      ac4[q & 3] = fmaf(w[q].y, hv.y, ac4[q & 3]);
      ac4[q & 3] = fmaf(w[q].z, hv.z, ac4[q & 3]);
      ac4[q & 3] = fmaf(w[q].w, hv.w, ac4[q & 3]);
    }
    float acc = (ac4[0] + ac4[1]) + (ac4[2] + ac4[3]);
    acc += __shfl_xor(acc, 1);
    if (half == 0) zlds[r] = acc + xwv;
    __syncthreads();
    const int par = (s + 1) & 1;
    const unsigned int tag = (unsigned int)(s + 1);
    if (t < 32) {
      float iv = zlds[t], fv = zlds[32 + t], gv = zlds[64 + t], ov = zlds[96 + t];
      creg = sigf(fv) * creg + sigf(iv) * tanhf(gv);
      float hn = sigf(ov) * tanhf(creg);
      int col = j * 32 + t;
      hlds[col] = hn;
      unsigned long long pk = ((unsigned long long)__float_as_uint(hn) << 32) | tag;
      store_l2(&fastw[par * DD + col], pk);  // fast path: XCD L2
      __hip_atomic_store(&sloww[par * DD + col], pk, __ATOMIC_RELAXED, __HIP_MEMORY_SCOPE_AGENT);
      hs[s * DD + col] = hn;                 // off critical path
    }
    // prefetch next step's xW during the poll phase
    float xw_next = (s + 1 < NN) ? xW[(s + 1) * 1024 + grow] : 0.f;
    if (t < 224) {
      int po = t >> 5;
      int peer = j + 1 + po; if (peer >= 8) peer -= 8;
      int col = peer * 32 + (t & 31);
      int idx = par * DD + col;
      unsigned long long v;
      bool got = false;
      for (int tries = 0; tries < 24; ++tries) {
        v = load_l2(&fastw[idx]);
        if ((unsigned int)(v & 0xffffffffULL) == tag) { got = true; break; }
      }
      if (!got) {
        while (((v = __hip_atomic_load(&sloww[idx], __ATOMIC_RELAXED,
                                       __HIP_MEMORY_SCOPE_AGENT)) & 0xffffffffULL) != tag)
          __builtin_amdgcn_s_sleep(2);
      }
      hlds[col] = __uint_as_float((unsigned int)(v >> 32));
    }
    __syncthreads();
    xwv = xw_next;
  }
}

// ---------------- final per-edge outputs ----------------
__global__ __launch_bounds__(256) void k_edges(const float* __restrict__ hs, const int* __restrict__ ei,
    const float* __restrict__ Wp, const float* __restrict__ bp,
    const float* __restrict__ Wc, const float* __restrict__ bc, float* __restrict__ out) {
  int widx = threadIdx.x >> 6, lane = threadIdx.x & 63;
  int k = blockIdx.x * 4 + widx;
  int sIdx = ei[k], dIdx = ei[EE + k];
  float4 u = ((const float4*)(hs + sIdx * DD))[lane];
  float4 v = ((const float4*)(hs + dIdx * DD))[lane];
  float4 wp = ((const float4*)Wp)[lane];
  float4 wc = ((const float4*)Wc)[lane];
  float x0 = u.x * v.x, x1 = u.y * v.y, x2 = u.z * v.z, x3 = u.w * v.w;
  float ap = x0 * wp.x + x1 * wp.y + x2 * wp.z + x3 * wp.w;
  float ac = x0 * wc.x + x1 * wc.y + x2 * wc.z + x3 * wc.w;
  #pragma unroll
  for (int msk = 1; msk < 64; msk <<= 1) { ap += __shfl_xor(ap, msk); ac += __shfl_xor(ac, msk); }
  if (lane == 0) { out[k] = ap + bp[0]; out[EE + k] = ac + bc[0]; }
}

extern "C" void kernel_launch(void* const* d_in, const int* in_sizes, int n_in,
                              void* d_out, int out_size, void* d_ws, size_t ws_size,
                              hipStream_t stream) {
  const float* x       = (const float*)d_in[0];
  const int* ei        = (const int*)d_in[1];
  const float* W1      = (const float*)d_in[3];
  const float* as1     = (const float*)d_in[4];
  const float* ad1     = (const float*)d_in[5];
  const float* b1      = (const float*)d_in[6];
  const float* W2      = (const float*)d_in[7];
  const float* as2     = (const float*)d_in[8];
  const float* ad2     = (const float*)d_in[9];
  const float* b2      = (const float*)d_in[10];
  const float* Wih     = (const float*)d_in[11];
  const float* Whh     = (const float*)d_in[12];
  const float* bih     = (const float*)d_in[13];
  const float* bhh     = (const float*)d_in[14];
  const float* Wp      = (const float*)d_in[15];
  const float* bp      = (const float*)d_in[16];
  const float* Wc      = (const float*)d_in[17];
  const float* bc      = (const float*)d_in[18];
  float* out = (float*)d_out;

  char* ws = (char*)d_ws;
  int* counts                = (int*)(ws + 0);        // 4 KB   [memset]
  int* ctrl                  = (int*)(ws + 4096);     // 4 KB   [memset]
  unsigned long long* fastw  = (unsigned long long*)(ws + 8192);   // 4 KB [memset]
  unsigned long long* sloww  = (unsigned long long*)(ws + 12288);  // 4 KB [memset]
  int* rowptr                = (int*)(ws + 16384);    // 8 KB
  int* cursor                = (int*)(ws + 24576);    // 4 KB
  int* csrc                  = (int*)(ws + 28672);    // 136 KB
  float* es                  = (float*)(ws + 167936); // 32 KB
  float* ed                  = (float*)(ws + 200704); // 32 KB
  float* buf0                = (float*)(ws + 233472); // 1 MB
  float* buf1                = (float*)(ws + 1282048);// 1 MB
  float* xW                  = (float*)(ws + 2330624);// 4 MB
  float* hsall               = (float*)(ws + 6524928);// 1 MB

  // zero counts + election ctrl + both handshake arrays (reset on every replay)
  hipMemsetAsync(ws, 0, 16384, stream);

  // CSR by dst (E edges + N self-loops)
  k_count  <<<(NEDGE + 255) / 256, 256, 0, stream>>>(ei, counts);
  k_scan   <<<1, 1024, 0, stream>>>(counts, rowptr, cursor);
  k_scatter<<<(NEDGE + 255) / 256, 256, 0, stream>>>(ei, cursor, csrc);

  // GAT layer 1 (graph (0,0) only)
  k_gemm<false, false><<<dim3(16, 4), 256, 0, stream>>>(x, W1, nullptr, nullptr, buf0, NN, DD, FF);
  k_att<<<NN, 256, 0, stream>>>(buf0, as1, ad1, es, ed);
  k_agg<<<NN * HH / 4, 256, 0, stream>>>(buf0, es, ed, b1, rowptr, csrc, buf1);

  // GAT layer 2
  k_gemm<false, false><<<dim3(16, 4), 256, 0, stream>>>(buf1, W2, nullptr, nullptr, buf0, NN, DD, DD);
  k_att<<<NN, 256, 0, stream>>>(buf0, as2, ad2, es, ed);
  k_agg<<<NN * HH / 4, 256, 0, stream>>>(buf0, es, ed, b2, rowptr, csrc, buf1);

  // LSTM input projection: xW[n, j] = h2[n,:]·Wih[j,:] + bih[j] + bhh[j]
  k_gemm<true, true><<<dim3(16, 16), 256, 0, stream>>>(buf1, Wih, bih, bhh, xW, NN, 1024, DD);

  // sequential recurrence; 512 candidates, 8 elected onto one XCD
  k_lstm<<<512, 256, 0, stream>>>(xW, Whh, fastw, sloww, ctrl, hsall);

  // final per-edge predictions
  k_edges<<<EE / 4, 256, 0, stream>>>(hsall, ei, Wp, bp, Wc, bc, out);
}

// Round 6
// 1976.203 us; speedup vs baseline: 3.5141x; 1.7426x over previous
//
#include <hip/hip_runtime.h>
#include <math.h>

#define NN 1024
#define FF 128
#define DD 256
#define HH 8
#define CC 32
#define EE 32768
#define NEDGE (EE + NN)

typedef unsigned int u32x4 __attribute__((ext_vector_type(4)));

__device__ __forceinline__ float sigf(float x) { return 1.0f / (1.0f + expf(-x)); }
// fast gates for the recurrence critical path (graceful at +-inf, no NaN)
__device__ __forceinline__ float fsig(float x) { return 1.0f / (1.0f + __expf(-x)); }
__device__ __forceinline__ float ftanh(float x) { return 2.0f / (1.0f + __expf(-2.0f * x)) - 1.0f; }

// XCD-L2-coherent accessors (sc0 = bypass L1 only; L2 is the XCD coherence point)
__device__ __forceinline__ void store_l2_u64(unsigned long long* p, unsigned long long v) {
  asm volatile("global_store_dwordx2 %0, %1, off sc0" :: "v"(p), "v"(v) : "memory");
}
__device__ __forceinline__ u32x4 load_l2_x4(const unsigned long long* p) {
  u32x4 r;
  asm volatile("global_load_dwordx4 %0, %1, off sc0\n\ts_waitcnt vmcnt(0)"
               : "=v"(r) : "v"(p) : "memory");
  return r;
}

// ---------------- CSR build (dst-indexed) ----------------
__global__ void k_count(const int* __restrict__ ei, int* __restrict__ count) {
  int k = blockIdx.x * blockDim.x + threadIdx.x;
  if (k >= NEDGE) return;
  int d = (k < EE) ? ei[EE + k] : (k - EE);
  atomicAdd(&count[d], 1);
}

__global__ void k_scan(const int* __restrict__ count, int* __restrict__ rowptr, int* __restrict__ cursor) {
  __shared__ int buf[NN];
  int t = threadIdx.x;
  int c = count[t];
  buf[t] = c;
  __syncthreads();
  for (int off = 1; off < NN; off <<= 1) {
    int add = (t >= off) ? buf[t - off] : 0;
    __syncthreads();
    buf[t] += add;
    __syncthreads();
  }
  int inc = buf[t];
  rowptr[t] = inc - c;
  cursor[t] = inc - c;
  if (t == NN - 1) rowptr[NN] = inc;
}

__global__ void k_scatter(const int* __restrict__ ei, int* __restrict__ cursor, int* __restrict__ csrc) {
  int k = blockIdx.x * blockDim.x + threadIdx.x;
  if (k >= NEDGE) return;
  int s, d;
  if (k < EE) { s = ei[k]; d = ei[EE + k]; }
  else        { s = k - EE; d = k - EE; }
  int pos = atomicAdd(&cursor[d], 1);
  csrc[pos] = s;
}

// ---------------- fp32 GEMM: C = A@B (or A@B^T) [+bias1+bias2] ----------------
template<bool BT, bool ADDB>
__global__ __launch_bounds__(256) void k_gemm(const float* __restrict__ A, const float* __restrict__ B,
    const float* __restrict__ bias1, const float* __restrict__ bias2, float* __restrict__ C,
    int M, int N, int K) {
  __shared__ float At[64][17];
  __shared__ float Bt[16][65];
  const int tid = threadIdx.x;
  const int m0 = blockIdx.x * 64, n0 = blockIdx.y * 64;
  const int tx = tid & 15, ty = tid >> 4;
  float acc[4][4] = {{0.f, 0.f, 0.f, 0.f}};
  for (int k0 = 0; k0 < K; k0 += 16) {
    {
      int rr = tid >> 2, kl = (tid & 3) * 4;
      float4 a = *(const float4*)(A + (m0 + rr) * K + k0 + kl);
      At[rr][kl] = a.x; At[rr][kl + 1] = a.y; At[rr][kl + 2] = a.z; At[rr][kl + 3] = a.w;
    }
    if (BT) {
      int nn = tid >> 2, kl = (tid & 3) * 4;
      float4 b = *(const float4*)(B + (n0 + nn) * K + k0 + kl);
      Bt[kl][nn] = b.x; Bt[kl + 1][nn] = b.y; Bt[kl + 2][nn] = b.z; Bt[kl + 3][nn] = b.w;
    } else {
      int kk = tid >> 4, nn = (tid & 15) * 4;
      float4 b = *(const float4*)(B + (k0 + kk) * N + n0 + nn);
      Bt[kk][nn] = b.x; Bt[kk][nn + 1] = b.y; Bt[kk][nn + 2] = b.z; Bt[kk][nn + 3] = b.w;
    }
    __syncthreads();
    #pragma unroll
    for (int kk = 0; kk < 16; ++kk) {
      float av[4], bv[4];
      #pragma unroll
      for (int i = 0; i < 4; ++i) av[i] = At[ty * 4 + i][kk];
      #pragma unroll
      for (int jj = 0; jj < 4; ++jj) bv[jj] = Bt[kk][tx * 4 + jj];
      #pragma unroll
      for (int i = 0; i < 4; ++i)
        #pragma unroll
        for (int jj = 0; jj < 4; ++jj)
          acc[i][jj] = fmaf(av[i], bv[jj], acc[i][jj]);
    }
    __syncthreads();
  }
  #pragma unroll
  for (int i = 0; i < 4; ++i) {
    #pragma unroll
    for (int jj = 0; jj < 4; ++jj) {
      int n = n0 + tx * 4 + jj;
      float v = acc[i][jj];
      if (ADDB) v += bias1[n] + bias2[n];
      C[(m0 + ty * 4 + i) * N + n] = v;
    }
  }
}

// ---------------- per-node attention scores es/ed ----------------
__global__ __launch_bounds__(256) void k_att(const float* __restrict__ h, const float* __restrict__ asrc,
    const float* __restrict__ adst, float* __restrict__ es, float* __restrict__ ed) {
  int n = blockIdx.x;
  int hd = threadIdx.x >> 5, c = threadIdx.x & 31;
  float hv = h[n * DD + hd * CC + c];
  float e1 = hv * asrc[hd * CC + c];
  float e2 = hv * adst[hd * CC + c];
  #pragma unroll
  for (int msk = 1; msk < 32; msk <<= 1) { e1 += __shfl_xor(e1, msk); e2 += __shfl_xor(e2, msk); }
  if (c == 0) { es[n * HH + hd] = e1; ed[n * HH + hd] = e2; }
}

// ---------------- per-(dst,head) softmax + aggregate (+bias, relu) ----------------
__global__ __launch_bounds__(256) void k_agg(const float* __restrict__ h, const float* __restrict__ es,
    const float* __restrict__ ed, const float* __restrict__ bias, const int* __restrict__ rowptr,
    const int* __restrict__ csrc, float* __restrict__ out) {
  int w = blockIdx.x * 4 + (threadIdx.x >> 6);
  int lane = threadIdx.x & 63;
  int n = w >> 3, hd = w & 7;
  int lo = rowptr[n], hi = rowptr[n + 1];
  float edn = ed[n * HH + hd];
  float m = -1e30f;
  for (int k = lo + lane; k < hi; k += 64) {
    int s = csrc[k];
    float e = es[s * HH + hd] + edn;
    e = (e > 0.f) ? e : 0.2f * e;
    m = fmaxf(m, e);
  }
  #pragma unroll
  for (int msk = 1; msk < 64; msk <<= 1) m = fmaxf(m, __shfl_xor(m, msk));
  float den = 0.f;
  for (int k = lo + lane; k < hi; k += 64) {
    int s = csrc[k];
    float e = es[s * HH + hd] + edn;
    e = (e > 0.f) ? e : 0.2f * e;
    den += expf(e - m);
  }
  #pragma unroll
  for (int msk = 1; msk < 64; msk <<= 1) den += __shfl_xor(den, msk);
  float inv = 1.0f / (den + 1e-16f);
  int c = lane & 31, halfsel = lane >> 5;
  float acc = 0.f;
  for (int k = lo + halfsel; k < hi; k += 2) {
    int s = csrc[k];
    float e = es[s * HH + hd] + edn;
    e = (e > 0.f) ? e : 0.2f * e;
    float al = expf(e - m) * inv;
    acc += al * h[s * DD + hd * CC + c];
  }
  acc += __shfl_down(acc, 32);
  if (lane < 32) {
    float v = acc + bias[hd * CC + c];
    out[n * DD + hd * CC + c] = fmaxf(v, 0.f);
  }
}

// ---------------- LSTM recurrence: 8 redundant same-XCD cohorts ----------------
// 64 blocks; cohort = bid&7 (round-robin => one XCD per cohort), role j = bid>>3.
// Each cohort runs the FULL recurrence redundantly (value-identical), so all
// cross-block traffic stays inside one XCD's L2 (sc0 self-tagged u64 publishes).
// Agent-scope mirror fallback => correct under ANY placement. ALL spin loops are
// budget-bounded (persistent per-thread budget): the kernel ALWAYS terminates —
// worst case wrong-answer diagnostic, never a hung container.
__global__ __launch_bounds__(256, 1) void k_lstm(const float* __restrict__ xW,
    const float* __restrict__ Whh, unsigned long long* __restrict__ fastw,
    unsigned long long* __restrict__ sloww, float* __restrict__ hs) {
  const int bid = blockIdx.x;
  const int coh = bid & 7;
  const int j = bid >> 3;
  unsigned long long* fw = fastw + coh * 2 * DD;
  unsigned long long* sw = sloww + coh * 2 * DD;
  const int t = threadIdx.x;
  const int r = t >> 1, half = t & 1;
  const int g = r >> 5, kl = r & 31;
  const int grow = g * 256 + j * 32 + kl;
  __shared__ float hlds[DD];
  __shared__ float zlds[128];

  // Whh slice pinned in VGPRs (asm outputs cannot be rematerialized/sunk)
  float4 w[32];
  {
    const float4* W4 = (const float4*)(Whh + grow * DD + half * 128);
    #pragma unroll
    for (int q = 0; q < 32; ++q)
      asm volatile("global_load_dwordx4 %0, %1, off" : "=v"(w[q]) : "v"(W4 + q));
    asm volatile("s_waitcnt vmcnt(0)" ::: "memory");
  }
  if (t < DD) hlds[t] = 0.f;
  float creg = 0.f;
  float xwv = xW[grow];
  int ftries = 48, miss = 0;
  int bud = 1 << 24;  // persistent spin budget: hang-proof
  __syncthreads();

  for (int s = 0; s < NN; ++s) {
    // ---- dot: z[grow] partial over k-half (hlds reads are wave-broadcast) ----
    const float4* h4 = ((const float4*)hlds) + half * 32;
    float ac4[4] = {0.f, 0.f, 0.f, 0.f};
    #pragma unroll
    for (int q = 0; q < 32; ++q) {
      float4 hv = h4[q];
      ac4[q & 3] = fmaf(w[q].x, hv.x, ac4[q & 3]);
      ac4[q & 3] = fmaf(w[q].y, hv.y, ac4[q & 3]);
      ac4[q & 3] = fmaf(w[q].z, hv.z, ac4[q & 3]);
      ac4[q & 3] = fmaf(w[q].w, hv.w, ac4[q & 3]);
    }
    float acc = (ac4[0] + ac4[1]) + (ac4[2] + ac4[3]);
    acc += __shfl_xor(acc, 1);
    if (half == 0) zlds[r] = acc + xwv;
    __syncthreads();

    const int par = (s + 1) & 1;
    const unsigned int tag = (unsigned int)(s + 1);
    float xw_next = (s + 1 < NN) ? xW[(s + 1) * 1024 + grow] : 0.f;  // prefetch

    if (t < 32) {
      // ---- gates + publish (wave 0 lanes 0-31; never polls) ----
      float iv = zlds[t], fv = zlds[32 + t], gv = zlds[64 + t], ov = zlds[96 + t];
      creg = fsig(fv) * creg + fsig(iv) * ftanh(gv);
      float hn = fsig(ov) * ftanh(creg);
      int col = j * 32 + t;
      hlds[col] = hn;
      unsigned long long pk = ((unsigned long long)__float_as_uint(hn) << 32) | tag;
      store_l2_u64(&fw[par * DD + col], pk);   // fast: own XCD L2
      __hip_atomic_store(&sw[par * DD + col], pk, __ATOMIC_RELAXED, __HIP_MEMORY_SCOPE_AGENT);
      hs[s * DD + col] = hn;                   // off critical path (identical dup writes)
    } else if (t >= 64 && t < 176) {
      // ---- pollers: waves 1-2; 112 threads x col-pair = 7 peers x 32 cols ----
      int pi = t - 64;
      int peer = j + 1 + (pi >> 4); if (peer >= 8) peer -= 8;
      int col0 = peer * 32 + ((pi & 15) << 1);
      int idx = par * DD + col0;
      u32x4 v; bool got = false;
      for (int tr = 0; tr < ftries; ++tr) {
        v = load_l2_x4(&fw[idx]);
        if (v.x == tag && v.z == tag) { got = true; break; }
      }
      if (!got) {
        ++miss;
        unsigned long long a, b;
        for (;;) {
          a = __hip_atomic_load(&sw[idx], __ATOMIC_RELAXED, __HIP_MEMORY_SCOPE_AGENT);
          if ((unsigned int)(a & 0xffffffffULL) == tag) break;
          if (--bud <= 0) break;
          __builtin_amdgcn_s_sleep(1);
        }
        for (;;) {
          b = __hip_atomic_load(&sw[idx + 1], __ATOMIC_RELAXED, __HIP_MEMORY_SCOPE_AGENT);
          if ((unsigned int)(b & 0xffffffffULL) == tag) break;
          if (--bud <= 0) break;
          __builtin_amdgcn_s_sleep(1);
        }
        v.y = (unsigned int)(a >> 32);
        v.w = (unsigned int)(b >> 32);
        if (miss >= 2 && ftries > 2) ftries = 2;  // not co-located: stop wasting fast tries
      }
      hlds[col0] = __uint_as_float(v.y);
      hlds[col0 + 1] = __uint_as_float(v.w);
    }
    __syncthreads();
    xwv = xw_next;
  }
}

// ---------------- final per-edge outputs ----------------
__global__ __launch_bounds__(256) void k_edges(const float* __restrict__ hs, const int* __restrict__ ei,
    const float* __restrict__ Wp, const float* __restrict__ bp,
    const float* __restrict__ Wc, const float* __restrict__ bc, float* __restrict__ out) {
  int widx = threadIdx.x >> 6, lane = threadIdx.x & 63;
  int k = blockIdx.x * 4 + widx;
  int sIdx = ei[k], dIdx = ei[EE + k];
  float4 u = ((const float4*)(hs + sIdx * DD))[lane];
  float4 v = ((const float4*)(hs + dIdx * DD))[lane];
  float4 wp = ((const float4*)Wp)[lane];
  float4 wc = ((const float4*)Wc)[lane];
  float x0 = u.x * v.x, x1 = u.y * v.y, x2 = u.z * v.z, x3 = u.w * v.w;
  float ap = x0 * wp.x + x1 * wp.y + x2 * wp.z + x3 * wp.w;
  float ac = x0 * wc.x + x1 * wc.y + x2 * wc.z + x3 * wc.w;
  #pragma unroll
  for (int msk = 1; msk < 64; msk <<= 1) { ap += __shfl_xor(ap, msk); ac += __shfl_xor(ac, msk); }
  if (lane == 0) { out[k] = ap + bp[0]; out[EE + k] = ac + bc[0]; }
}

extern "C" void kernel_launch(void* const* d_in, const int* in_sizes, int n_in,
                              void* d_out, int out_size, void* d_ws, size_t ws_size,
                              hipStream_t stream) {
  const float* x       = (const float*)d_in[0];
  const int* ei        = (const int*)d_in[1];
  const float* W1      = (const float*)d_in[3];
  const float* as1     = (const float*)d_in[4];
  const float* ad1     = (const float*)d_in[5];
  const float* b1      = (const float*)d_in[6];
  const float* W2      = (const float*)d_in[7];
  const float* as2     = (const float*)d_in[8];
  const float* ad2     = (const float*)d_in[9];
  const float* b2      = (const float*)d_in[10];
  const float* Wih     = (const float*)d_in[11];
  const float* Whh     = (const float*)d_in[12];
  const float* bih     = (const float*)d_in[13];
  const float* bhh     = (const float*)d_in[14];
  const float* Wp      = (const float*)d_in[15];
  const float* bp      = (const float*)d_in[16];
  const float* Wc      = (const float*)d_in[17];
  const float* bc      = (const float*)d_in[18];
  float* out = (float*)d_out;

  char* ws = (char*)d_ws;
  int* counts                = (int*)(ws + 0);          // 4 KB  [memset]
  unsigned long long* fastw  = (unsigned long long*)(ws + 4096);   // 32 KB [memset] 8 cohorts x 2 x 256
  unsigned long long* sloww  = (unsigned long long*)(ws + 36864);  // 32 KB [memset]
  int* rowptr                = (int*)(ws + 69632);      // 8 KB
  int* cursor                = (int*)(ws + 77824);      // 4 KB
  int* csrc                  = (int*)(ws + 81920);      // 136 KB
  float* es                  = (float*)(ws + 221184);   // 32 KB
  float* ed                  = (float*)(ws + 253952);   // 32 KB
  float* buf0                = (float*)(ws + 286720);   // 1 MB
  float* buf1                = (float*)(ws + 1335296);  // 1 MB
  float* xW                  = (float*)(ws + 2383872);  // 4 MB
  float* hsall               = (float*)(ws + 6578176);  // 1 MB

  // zero counts + both handshake arrays (in-graph => reset every replay)
  hipMemsetAsync(ws, 0, 69632, stream);

  // CSR by dst (E edges + N self-loops)
  k_count  <<<(NEDGE + 255) / 256, 256, 0, stream>>>(ei, counts);
  k_scan   <<<1, 1024, 0, stream>>>(counts, rowptr, cursor);
  k_scatter<<<(NEDGE + 255) / 256, 256, 0, stream>>>(ei, cursor, csrc);

  // GAT layer 1 (graph (0,0) only)
  k_gemm<false, false><<<dim3(16, 4), 256, 0, stream>>>(x, W1, nullptr, nullptr, buf0, NN, DD, FF);
  k_att<<<NN, 256, 0, stream>>>(buf0, as1, ad1, es, ed);
  k_agg<<<NN * HH / 4, 256, 0, stream>>>(buf0, es, ed, b1, rowptr, csrc, buf1);

  // GAT layer 2
  k_gemm<false, false><<<dim3(16, 4), 256, 0, stream>>>(buf1, W2, nullptr, nullptr, buf0, NN, DD, DD);
  k_att<<<NN, 256, 0, stream>>>(buf0, as2, ad2, es, ed);
  k_agg<<<NN * HH / 4, 256, 0, stream>>>(buf0, es, ed, b2, rowptr, csrc, buf1);

  // LSTM input projection: xW[n, j] = h2[n,:]·Wih[j,:] + bih[j] + bhh[j]
  k_gemm<true, true><<<dim3(16, 16), 256, 0, stream>>>(buf1, Wih, bih, bhh, xW, NN, 1024, DD);

  // sequential recurrence: 8 redundant cohorts x 8 roles (round-robin XCD mapping)
  k_lstm<<<64, 256, 0, stream>>>(xW, Whh, fastw, sloww, hsall);

  // final per-edge predictions
  k_edges<<<EE / 4, 256, 0, stream>>>(hsall, ei, Wp, bp, Wc, bc, out);
}